// Round 18
// baseline (150.568 us; speedup 1.0000x reference)
//
#include <hip/hip_runtime.h>

// GRU (B=4096, T=512, I=1, H=32) + FC(32->12): unit-split 2-wave blocks,
// DUAL independent chains per lane (ILP fills the chain-latency idle).
//
// R16/R17 plateau: 572 cy/step, issue 74% (VALU 56 + MFMA 18), ~26% idle =
// serial chain (ds_read -> MFMA -> sel -> 3exp+2rcp chain -> cvt -> ds_write
// -> barrier) exposed at 2 waves/SIMD. More waves re-adds the MFMA
// replication tax (R11/R14). Fix: TWO independent GRU chains per lane -
// block owns 8 rows (chain A: rows 0-3, chain B: rows 4-7), same unit-split
// (wave w owns units [16w,16w+16)), same shared weight/bias registers.
// Per step: 3+3 MFMAs (per-row MFMA cost unchanged), two independent
// sel+gate chains interleaved by the scheduler, ONE barrier for both
// exchanges (barrier cost per row halves). 512 blocks x 2 waves = 1024
// waves = 1 wave/SIMD at 256-VGPR budget (in-lane ILP replaces TLP; this is
// the chain-latency regime where ILP pays - unlike R5's issue-bound regime).
//
// Exchange per chain: ds_write_b16 + (lgkmcnt-only barrier) + ds_read_b128
// directly into B (slot map k(lg,i)=8lg+i; A and B share the map; MFMA
// contracts slot-vs-slot so any consistent bijection is exact).
// h stays f32 in registers; f16 only as the MFMA B operand. exp folding:
// r,z rows scaled by -log2e, n rows by +2log2e -> raw v_exp_f32 + v_rcp;
// product-rcp sigmoid fusion: one rcp serves r and z.

namespace {

typedef _Float16 f16;
typedef _Float16 f16x8 __attribute__((ext_vector_type(8)));
typedef float    f32x4 __attribute__((ext_vector_type(4)));

constexpr int kT = 512;
constexpr float kL2E = 1.4426950408889634f;

__device__ __forceinline__ float fast_exp2(float a) {
#if __has_builtin(__builtin_amdgcn_exp2f)
    return __builtin_amdgcn_exp2f(a);
#else
    return exp2f(a);
#endif
}
__device__ __forceinline__ float fast_rcp(float a) {
#if __has_builtin(__builtin_amdgcn_rcpf)
    return __builtin_amdgcn_rcpf(a);
#else
    return 1.0f / a;
#endif
}

// 4-way select a[(b1<<1)|b0] via 3 cndmask
__device__ __forceinline__ float sel4(const f32x4& a, bool b0, bool b1) {
    const float x01 = b0 ? a[1] : a[0];
    const float x23 = b0 ? a[3] : a[2];
    return b1 ? x23 : x01;
}

__global__ __launch_bounds__(128)
__attribute__((amdgpu_waves_per_eu(1, 1)))
void gru_2w2c(
    const float* __restrict__ x,      // [4096, 512]
    const float* __restrict__ w_ih,   // [96]
    const float* __restrict__ w_hh,   // [96, 32]
    const float* __restrict__ b_ih,   // [96]
    const float* __restrict__ b_hh,   // [96]
    const float* __restrict__ fc_w,   // [12, 32]
    const float* __restrict__ fc_b,   // [12]
    float* __restrict__ out)          // [4096, 12]
{
    __shared__ f16   hbufA[2][4][32]; // chain A h exchange (double-buffered)
    __shared__ f16   hbufB[2][4][32]; // chain B
    __shared__ float hf[8 * 33];      // FC epilogue

    const int tid  = threadIdx.x;
    const int w    = tid >> 6;        // wave id: unit half [16w, 16w+16)
    const int lane = tid & 63;
    const int c    = lane & 15;       // B column = 4q + j
    const int lg   = lane >> 4;       // slot group: B slots = units 8lg..+7
    const int q    = c >> 2;          // owned-reg id 0..3
    const int j    = c & 3;           // batch row (within each chain's 4)
    const int blk  = blockIdx.x;

    // ---- A fragments: 3 gates x this wave's 16-unit tile, K=32,
    //      slot map k(lg,i) = 8lg + i, scale-folded (shared by chains) ----
    f16x8 wA[3];
#pragma unroll
    for (int g = 0; g < 3; ++g) {
        const float s = (g < 2) ? -kL2E : 2.0f * kL2E;
        f16x8 f;
#pragma unroll
        for (int i = 0; i < 8; ++i)
            f[i] = (f16)(s * w_hh[(g * 32 + w * 16 + c) * 32 + 8 * lg + i]);
        wA[g] = f;
    }

    // ---- bias C operands: C[reg v] = bias(unit 16w + 4lg + v) ----
    f32x4 biasC[3];
#pragma unroll
    for (int v = 0; v < 4; ++v) {
        const int u = w * 16 + 4 * lg + v;
        biasC[0][v] = -kL2E * (b_ih[u] + b_hh[u]);
        biasC[1][v] = -kL2E * (b_ih[u + 32] + b_hh[u + 32]);
        biasC[2][v] = 2.0f * kL2E * b_hh[u + 64];
    }

    // ---- this lane's unit u = 16w + 4lg + q (shared by both chains) ----
    const int u = w * 16 + 4 * lg + q;
    const float cwr = -kL2E * w_ih[u];
    const float cwz = -kL2E * w_ih[u + 32];
    const float cwn = 2.0f * kL2E * w_ih[u + 64];
    const float cbn = 2.0f * kL2E * b_ih[u + 64];
    const bool b0 = (q & 1) != 0;
    const bool b1 = (q & 2) != 0;

    // ---- state: two independent chains ----
    float hA = 0.0f, hB = 0.0f;
    f16x8 BA = {(f16)0, (f16)0, (f16)0, (f16)0,
                (f16)0, (f16)0, (f16)0, (f16)0};
    f16x8 BB = BA;

    const float4* xrowA = reinterpret_cast<const float4*>(
        x + ((size_t)blk * 8 + j) * kT);
    const float4* xrowB = reinterpret_cast<const float4*>(
        x + ((size_t)blk * 8 + 4 + j) * kT);
    float4 xcurA = xrowA[0];
    float4 xcurB = xrowB[0];

    for (int t0 = 0; t0 < kT; t0 += 4) {
        const int nq = (t0 + 4 < kT) ? (t0 >> 2) + 1 : (t0 >> 2);
        float4 xnextA = xrowA[nq];
        float4 xnextB = xrowB[nq];

#pragma unroll
        for (int tt = 0; tt < 4; ++tt) {
            const float xtA = (tt == 0) ? xcurA.x : (tt == 1) ? xcurA.y
                            : (tt == 2) ? xcurA.z : xcurA.w;
            const float xtB = (tt == 0) ? xcurB.x : (tt == 1) ? xcurB.y
                            : (tt == 2) ? xcurB.z : xcurB.w;
            const int buf = tt & 1;   // compile-time parity

            // ---- 6 MFMAs: 3 per chain, bias via C ----
            const f32x4 aRA = __builtin_amdgcn_mfma_f32_16x16x32_f16(wA[0], BA, biasC[0], 0, 0, 0);
            const f32x4 aRB = __builtin_amdgcn_mfma_f32_16x16x32_f16(wA[0], BB, biasC[0], 0, 0, 0);
            const f32x4 aZA = __builtin_amdgcn_mfma_f32_16x16x32_f16(wA[1], BA, biasC[1], 0, 0, 0);
            const f32x4 aZB = __builtin_amdgcn_mfma_f32_16x16x32_f16(wA[1], BB, biasC[1], 0, 0, 0);
            const f32x4 aNA = __builtin_amdgcn_mfma_f32_16x16x32_f16(wA[2], BA, biasC[2], 0, 0, 0);
            const f32x4 aNB = __builtin_amdgcn_mfma_f32_16x16x32_f16(wA[2], BB, biasC[2], 0, 0, 0);

            // ---- chain A gate update ----
            {
                const float pr = sel4(aRA, b0, b1);
                const float pz = sel4(aZA, b0, b1);
                const float pn = sel4(aNA, b0, b1);
                const float ar  = fmaf(xtA, cwr, pr);
                const float az  = fmaf(xtA, cwz, pz);
                const float inn = fmaf(xtA, cwn, cbn);
                const float sr = 1.0f + fast_exp2(ar);
                const float sz = 1.0f + fast_exp2(az);
                const float ip = fast_rcp(sr * sz);
                const float r  = ip * sz;
                const float z  = ip * sr;
                const float n = fmaf(-2.0f,
                    fast_rcp(1.0f + fast_exp2(fmaf(r, pn, inn))), 1.0f);
                hA = fmaf(z, hA - n, n);
            }
            // ---- chain B gate update (independent; scheduler interleaves) ----
            {
                const float pr = sel4(aRB, b0, b1);
                const float pz = sel4(aZB, b0, b1);
                const float pn = sel4(aNB, b0, b1);
                const float ar  = fmaf(xtB, cwr, pr);
                const float az  = fmaf(xtB, cwz, pz);
                const float inn = fmaf(xtB, cwn, cbn);
                const float sr = 1.0f + fast_exp2(ar);
                const float sz = 1.0f + fast_exp2(az);
                const float ip = fast_rcp(sr * sz);
                const float r  = ip * sz;
                const float z  = ip * sr;
                const float n = fmaf(-2.0f,
                    fast_rcp(1.0f + fast_exp2(fmaf(r, pn, inn))), 1.0f);
                hB = fmaf(z, hB - n, n);
            }

            // ---- exchange both chains: ONE barrier per step ----
            hbufA[buf][j][u] = (f16)hA;
            hbufB[buf][j][u] = (f16)hB;
            asm volatile("s_waitcnt lgkmcnt(0)" ::: "memory");
            __builtin_amdgcn_s_barrier();
            BA = *reinterpret_cast<const f16x8*>(&hbufA[buf][j][8 * lg]);
            BB = *reinterpret_cast<const f16x8*>(&hbufB[buf][j][8 * lg]);
        }
        xcurA = xnextA;
        xcurB = xnextB;
    }

    // ---- FC epilogue: h[8][32] f32 in LDS, 96 outputs ----
    hf[j * 33 + u]       = hA;
    hf[(j + 4) * 33 + u] = hB;
    __syncthreads();
    if (tid < 96) {
        const int row = tid / 12, o = tid % 12;
        float acc = fc_b[o];
#pragma unroll
        for (int k = 0; k < 32; ++k)
            acc = fmaf(fc_w[o * 32 + k], hf[row * 33 + k], acc);
        out[((size_t)blk * 8 + row) * 12 + o] = acc;
    }
}

}  // namespace

extern "C" void kernel_launch(void* const* d_in, const int* in_sizes, int n_in,
                              void* d_out, int out_size, void* d_ws, size_t ws_size,
                              hipStream_t stream) {
    const float* x    = (const float*)d_in[0];
    const float* w_ih = (const float*)d_in[1];
    const float* w_hh = (const float*)d_in[2];
    const float* b_ih = (const float*)d_in[3];
    const float* b_hh = (const float*)d_in[4];
    const float* fc_w = (const float*)d_in[5];
    const float* fc_b = (const float*)d_in[6];
    float* out = (float*)d_out;

    dim3 grid(512);    // 4096 rows / 8 per block
    dim3 block(128);   // 2 waves (unit-split), dual chains per lane
    gru_2w2c<<<grid, block, 0, stream>>>(x, w_ih, w_hh, b_ih, b_hh, fc_w, fc_b, out);
}

// Round 19
// 116.534 us; speedup vs baseline: 1.2921x; 1.2921x over previous
//
#include <hip/hip_runtime.h>

// GRU (B=4096, T=512, I=1, H=32) + FC(32->12): unit-split 2-wave blocks
// + s_setprio compute/exchange asymmetry.
//
// Structure = R16 verbatim (best: 107.5us bench): block = 128 threads =
// 2 waves, 4 batch rows; wave w owns hidden units [16w, 16w+16), runs
// 3 MFMAs (3 gates x its tile, K=32, bias in C) + ONE gate update/lane.
// 1024 blocks x 2 waves = 2048 waves = 2/SIMD; co-resident waves are from
// DIFFERENT blocks. Exchange: ds_write_b16 + __syncthreads + ds_read_b128
// straight into B (slot map k(lg,i)=8lg+i shared by A and B; MFMA contracts
// slot-vs-slot so any consistent bijection is exact).
//
// NEW vs R16: s_setprio(1) around the MFMA+gate region, setprio(0) around
// the write/barrier/read region. Mechanism (m191 attn precedent, same
// regime: independent blocks, 2 waves/SIMD): a wave in its compute phase
// preempts the co-resident wave sitting in exchange, driving the pair into
// anti-phase so their serial chains interleave instead of lockstepping.
// R5/R18 closed the ILP route; R13/R14/R16 closed the occupancy triangle -
// this is the last precedented lever on the R16 structure.
// h stays f32 in registers; f16 only as MFMA B operand. exp folding: r,z
// rows scaled by -log2e, n rows by +2log2e -> raw v_exp_f32 + v_rcp;
// product-rcp sigmoid fusion: one rcp serves r and z.

namespace {

typedef _Float16 f16;
typedef _Float16 f16x8 __attribute__((ext_vector_type(8)));
typedef float    f32x4 __attribute__((ext_vector_type(4)));

constexpr int kT = 512;
constexpr float kL2E = 1.4426950408889634f;

__device__ __forceinline__ float fast_exp2(float a) {
#if __has_builtin(__builtin_amdgcn_exp2f)
    return __builtin_amdgcn_exp2f(a);
#else
    return exp2f(a);
#endif
}
__device__ __forceinline__ float fast_rcp(float a) {
#if __has_builtin(__builtin_amdgcn_rcpf)
    return __builtin_amdgcn_rcpf(a);
#else
    return 1.0f / a;
#endif
}

// 4-way select a[(b1<<1)|b0] via 3 cndmask
__device__ __forceinline__ float sel4(const f32x4& a, bool b0, bool b1) {
    const float x01 = b0 ? a[1] : a[0];
    const float x23 = b0 ? a[3] : a[2];
    return b1 ? x23 : x01;
}

__global__ __launch_bounds__(128)
__attribute__((amdgpu_waves_per_eu(2, 2)))
void gru_2wp(
    const float* __restrict__ x,      // [4096, 512]
    const float* __restrict__ w_ih,   // [96]
    const float* __restrict__ w_hh,   // [96, 32]
    const float* __restrict__ b_ih,   // [96]
    const float* __restrict__ b_hh,   // [96]
    const float* __restrict__ fc_w,   // [12, 32]
    const float* __restrict__ fc_b,   // [12]
    float* __restrict__ out)          // [4096, 12]
{
    __shared__ f16   hbuf[2][4][32];  // double-buffered h exchange
    __shared__ float hf[4 * 33];      // FC epilogue

    const int tid  = threadIdx.x;
    const int w    = tid >> 6;        // wave id: unit half [16w, 16w+16)
    const int lane = tid & 63;
    const int c    = lane & 15;       // B column = 4q + j
    const int lg   = lane >> 4;       // slot group: B slots = units 8lg..+7
    const int q    = c >> 2;          // owned-reg id 0..3
    const int j    = c & 3;           // batch row owned
    const int blk  = blockIdx.x;

    // ---- A fragments: 3 gates x this wave's 16-unit tile, K=32,
    //      slot map k(lg,i) = 8lg + i, scale-folded ----
    f16x8 wA[3];
#pragma unroll
    for (int g = 0; g < 3; ++g) {
        const float s = (g < 2) ? -kL2E : 2.0f * kL2E;
        f16x8 f;
#pragma unroll
        for (int i = 0; i < 8; ++i)
            f[i] = (f16)(s * w_hh[(g * 32 + w * 16 + c) * 32 + 8 * lg + i]);
        wA[g] = f;
    }

    // ---- bias C operands: C[reg v] = bias(unit 16w + 4lg + v) ----
    f32x4 biasC[3];
#pragma unroll
    for (int v = 0; v < 4; ++v) {
        const int u = w * 16 + 4 * lg + v;
        biasC[0][v] = -kL2E * (b_ih[u] + b_hh[u]);
        biasC[1][v] = -kL2E * (b_ih[u + 32] + b_hh[u + 32]);
        biasC[2][v] = 2.0f * kL2E * b_hh[u + 64];
    }

    // ---- this lane's unit u = 16w + 4lg + q ----
    const int u = w * 16 + 4 * lg + q;
    const float cwr = -kL2E * w_ih[u];
    const float cwz = -kL2E * w_ih[u + 32];
    const float cwn = 2.0f * kL2E * w_ih[u + 64];
    const float cbn = 2.0f * kL2E * b_ih[u + 64];
    const bool b0 = (q & 1) != 0;
    const bool b1 = (q & 2) != 0;

    // ---- state ----
    float h = 0.0f;
    f16x8 B = {(f16)0, (f16)0, (f16)0, (f16)0,
               (f16)0, (f16)0, (f16)0, (f16)0};

    const float4* xrow = reinterpret_cast<const float4*>(
        x + ((size_t)blk * 4 + j) * kT);
    float4 xcur = xrow[0];

    for (int t0 = 0; t0 < kT; t0 += 4) {
        const int nq = (t0 + 4 < kT) ? (t0 >> 2) + 1 : (t0 >> 2);
        float4 xnext = xrow[nq];

#pragma unroll
        for (int tt = 0; tt < 4; ++tt) {
            const float xt = (tt == 0) ? xcur.x : (tt == 1) ? xcur.y
                           : (tt == 2) ? xcur.z : xcur.w;
            const int buf = tt & 1;   // compile-time parity (t0 is even)

            // ---- compute phase: high priority ----
            __builtin_amdgcn_s_setprio(1);

            // 3 MFMAs: this wave's gate tiles, bias via C
            const f32x4 aR = __builtin_amdgcn_mfma_f32_16x16x32_f16(wA[0], B, biasC[0], 0, 0, 0);
            const f32x4 aZ = __builtin_amdgcn_mfma_f32_16x16x32_f16(wA[1], B, biasC[1], 0, 0, 0);
            const f32x4 aN = __builtin_amdgcn_mfma_f32_16x16x32_f16(wA[2], B, biasC[2], 0, 0, 0);

            // one gate update (select reg q, product-rcp fusion)
            const float pr = sel4(aR, b0, b1);
            const float pz = sel4(aZ, b0, b1);
            const float pn = sel4(aN, b0, b1);
            const float ar  = fmaf(xt, cwr, pr);
            const float az  = fmaf(xt, cwz, pz);
            const float inn = fmaf(xt, cwn, cbn);
            const float sr = 1.0f + fast_exp2(ar);
            const float sz = 1.0f + fast_exp2(az);
            const float ip = fast_rcp(sr * sz);
            const float r  = ip * sz;
            const float z  = ip * sr;
            const float n = fmaf(-2.0f,
                fast_rcp(1.0f + fast_exp2(fmaf(r, pn, inn))), 1.0f);
            h = fmaf(z, h - n, n);

            // ---- exchange phase: low priority ----
            __builtin_amdgcn_s_setprio(0);
            hbuf[buf][j][u] = (f16)h;
            __syncthreads();
            B = *reinterpret_cast<const f16x8*>(&hbuf[buf][j][8 * lg]);
        }
        xcur = xnext;
    }

    // ---- FC epilogue: h[4][32] f32 in LDS (128 lanes = 128 h values) ----
    hf[j * 33 + u] = h;
    __syncthreads();
    if (tid < 48) {
        const int row = tid / 12, o = tid % 12;
        float acc = fc_b[o];
#pragma unroll
        for (int k = 0; k < 32; ++k)
            acc = fmaf(fc_w[o * 32 + k], hf[row * 33 + k], acc);
        out[((size_t)blk * 4 + row) * 12 + o] = acc;
    }
}

}  // namespace

extern "C" void kernel_launch(void* const* d_in, const int* in_sizes, int n_in,
                              void* d_out, int out_size, void* d_ws, size_t ws_size,
                              hipStream_t stream) {
    const float* x    = (const float*)d_in[0];
    const float* w_ih = (const float*)d_in[1];
    const float* w_hh = (const float*)d_in[2];
    const float* b_ih = (const float*)d_in[3];
    const float* b_hh = (const float*)d_in[4];
    const float* fc_w = (const float*)d_in[5];
    const float* fc_b = (const float*)d_in[6];
    float* out = (float*)d_out;

    dim3 grid(1024);   // 4096 rows / 4 per block
    dim3 block(128);   // 2 waves: unit-split, 2048 waves = 2/SIMD
    gru_2wp<<<grid, block, 0, stream>>>(x, w_ih, w_hh, b_ih, b_hh, fc_w, fc_b, out);
}

// Round 20
// 107.783 us; speedup vs baseline: 1.3970x; 1.0812x over previous
//
#include <hip/hip_runtime.h>

// GRU (B=4096, T=512, I=1, H=32) + FC(32->12): unit-split 2-wave blocks.
// FINAL KERNEL = R16 verbatim (measured best: 107.5us bench, 121us dispatch).
//
// Block = 128 threads = 2 waves, owns 4 batch rows. Wave w owns hidden
// units [16w, 16w+16): it runs 3 MFMAs (3 gates x its 16-unit tile, K=32,
// bias preloaded in the C operand) and ONE gate update per lane.
// 1024 blocks x 2 waves = 2048 waves = 2/SIMD; co-resident waves come from
// DIFFERENT blocks so they do not phase-lock; MFMA work is SPLIT (not
// replicated) across the waves - per-SIMD MFMA cost equals the single-wave
// design (R13) while per-wave gate VALU halves.
//
// Cross-wave h exchange per step: 1 ds_write_b16 (own unit) + 1
// __syncthreads + 1 ds_read_b128 which lands DIRECTLY in the B operand
// (slot map k(lg,i) = 8*lg + i; A uses the same map; MFMA contracts
// slot-vs-slot so any consistent slot->k bijection is exact - validated
// R12/R13). hbuf double-buffered with compile-time parity (tt&1); the
// B-read is consumed by the MFMA before the next write+barrier -> WAR-safe
// with one barrier per step. 2-way bank aliases only (free).
//
// Ownership: lane (lg = L>>4, c = L&15), q = c>>2, j = c&3 owns unit
// u = 16w + 4lg + q, row j; select reg q via 3-cndmask tree.
// h stays f32 in registers (recurrence never rounded); f16 only as the
// MFMA B operand. exp folding: r,z weight rows pre-scaled by -log2e, n rows
// by +2log2e -> activations use raw v_exp_f32 (2^x) + v_rcp; product-rcp
// sigmoid fusion: one rcp serves both r and z.
//
// Closed levers (measured): vector f16 = f32 FLOP rate (R3-R6); MFMA
// replication tax at 2+ waves/SIMD (R11/R14); fork-join barriers (R7);
// 1-wave latency exposure (R8/R13); ILP-for-TLP swap (R5/R18); vmcnt-free
// barrier (R17 null); s_setprio (R19, -8%: barrier rendezvous defeats
// priority anti-phasing).

namespace {

typedef _Float16 f16;
typedef _Float16 f16x8 __attribute__((ext_vector_type(8)));
typedef float    f32x4 __attribute__((ext_vector_type(4)));

constexpr int kT = 512;
constexpr float kL2E = 1.4426950408889634f;

__device__ __forceinline__ float fast_exp2(float a) {
#if __has_builtin(__builtin_amdgcn_exp2f)
    return __builtin_amdgcn_exp2f(a);
#else
    return exp2f(a);
#endif
}
__device__ __forceinline__ float fast_rcp(float a) {
#if __has_builtin(__builtin_amdgcn_rcpf)
    return __builtin_amdgcn_rcpf(a);
#else
    return 1.0f / a;
#endif
}

// 4-way select a[(b1<<1)|b0] via 3 cndmask
__device__ __forceinline__ float sel4(const f32x4& a, bool b0, bool b1) {
    const float x01 = b0 ? a[1] : a[0];
    const float x23 = b0 ? a[3] : a[2];
    return b1 ? x23 : x01;
}

__global__ __launch_bounds__(128)
__attribute__((amdgpu_waves_per_eu(2, 2)))
void gru_2w(
    const float* __restrict__ x,      // [4096, 512]
    const float* __restrict__ w_ih,   // [96]
    const float* __restrict__ w_hh,   // [96, 32]
    const float* __restrict__ b_ih,   // [96]
    const float* __restrict__ b_hh,   // [96]
    const float* __restrict__ fc_w,   // [12, 32]
    const float* __restrict__ fc_b,   // [12]
    float* __restrict__ out)          // [4096, 12]
{
    __shared__ f16   hbuf[2][4][32];  // double-buffered h exchange
    __shared__ float hf[4 * 33];      // FC epilogue

    const int tid  = threadIdx.x;
    const int w    = tid >> 6;        // wave id: unit half [16w, 16w+16)
    const int lane = tid & 63;
    const int c    = lane & 15;       // B column = 4q + j
    const int lg   = lane >> 4;       // slot group: B slots = units 8lg..+7
    const int q    = c >> 2;          // owned-reg id 0..3
    const int j    = c & 3;           // batch row owned
    const int blk  = blockIdx.x;

    // ---- A fragments: 3 gates x this wave's 16-unit tile, K=32,
    //      slot map k(lg,i) = 8lg + i, scale-folded ----
    f16x8 wA[3];
#pragma unroll
    for (int g = 0; g < 3; ++g) {
        const float s = (g < 2) ? -kL2E : 2.0f * kL2E;
        f16x8 f;
#pragma unroll
        for (int i = 0; i < 8; ++i)
            f[i] = (f16)(s * w_hh[(g * 32 + w * 16 + c) * 32 + 8 * lg + i]);
        wA[g] = f;
    }

    // ---- bias C operands: C[reg v] = bias(unit 16w + 4lg + v) ----
    f32x4 biasC[3];
#pragma unroll
    for (int v = 0; v < 4; ++v) {
        const int u = w * 16 + 4 * lg + v;
        biasC[0][v] = -kL2E * (b_ih[u] + b_hh[u]);
        biasC[1][v] = -kL2E * (b_ih[u + 32] + b_hh[u + 32]);
        biasC[2][v] = 2.0f * kL2E * b_hh[u + 64];
    }

    // ---- this lane's unit u = 16w + 4lg + q ----
    const int u = w * 16 + 4 * lg + q;
    const float cwr = -kL2E * w_ih[u];
    const float cwz = -kL2E * w_ih[u + 32];
    const float cwn = 2.0f * kL2E * w_ih[u + 64];
    const float cbn = 2.0f * kL2E * b_ih[u + 64];
    const bool b0 = (q & 1) != 0;
    const bool b1 = (q & 2) != 0;

    // ---- state ----
    float h = 0.0f;
    f16x8 B = {(f16)0, (f16)0, (f16)0, (f16)0,
               (f16)0, (f16)0, (f16)0, (f16)0};

    const float4* xrow = reinterpret_cast<const float4*>(
        x + ((size_t)blk * 4 + j) * kT);
    float4 xcur = xrow[0];

    for (int t0 = 0; t0 < kT; t0 += 4) {
        const int nq = (t0 + 4 < kT) ? (t0 >> 2) + 1 : (t0 >> 2);
        float4 xnext = xrow[nq];

#pragma unroll
        for (int tt = 0; tt < 4; ++tt) {
            const float xt = (tt == 0) ? xcur.x : (tt == 1) ? xcur.y
                           : (tt == 2) ? xcur.z : xcur.w;
            const int buf = tt & 1;   // compile-time parity (t0 is even)

            // ---- 3 MFMAs: this wave's gate tiles, bias via C ----
            const f32x4 aR = __builtin_amdgcn_mfma_f32_16x16x32_f16(wA[0], B, biasC[0], 0, 0, 0);
            const f32x4 aZ = __builtin_amdgcn_mfma_f32_16x16x32_f16(wA[1], B, biasC[1], 0, 0, 0);
            const f32x4 aN = __builtin_amdgcn_mfma_f32_16x16x32_f16(wA[2], B, biasC[2], 0, 0, 0);

            // ---- one gate update (select reg q, product-rcp fusion) ----
            const float pr = sel4(aR, b0, b1);
            const float pz = sel4(aZ, b0, b1);
            const float pn = sel4(aN, b0, b1);
            const float ar  = fmaf(xt, cwr, pr);
            const float az  = fmaf(xt, cwz, pz);
            const float inn = fmaf(xt, cwn, cbn);
            const float sr = 1.0f + fast_exp2(ar);
            const float sz = 1.0f + fast_exp2(az);
            const float ip = fast_rcp(sr * sz);
            const float r  = ip * sz;
            const float z  = ip * sr;
            const float n = fmaf(-2.0f,
                fast_rcp(1.0f + fast_exp2(fmaf(r, pn, inn))), 1.0f);
            h = fmaf(z, h - n, n);

            // ---- exchange: write own unit, barrier, read full row ----
            hbuf[buf][j][u] = (f16)h;
            __syncthreads();
            B = *reinterpret_cast<const f16x8*>(&hbuf[buf][j][8 * lg]);
        }
        xcur = xnext;
    }

    // ---- FC epilogue: h[4][32] f32 in LDS (128 lanes = 128 h values) ----
    hf[j * 33 + u] = h;
    __syncthreads();
    if (tid < 48) {
        const int row = tid / 12, o = tid % 12;
        float acc = fc_b[o];
#pragma unroll
        for (int k = 0; k < 32; ++k)
            acc = fmaf(fc_w[o * 32 + k], hf[row * 33 + k], acc);
        out[((size_t)blk * 4 + row) * 12 + o] = acc;
    }
}

}  // namespace

extern "C" void kernel_launch(void* const* d_in, const int* in_sizes, int n_in,
                              void* d_out, int out_size, void* d_ws, size_t ws_size,
                              hipStream_t stream) {
    const float* x    = (const float*)d_in[0];
    const float* w_ih = (const float*)d_in[1];
    const float* w_hh = (const float*)d_in[2];
    const float* b_ih = (const float*)d_in[3];
    const float* b_hh = (const float*)d_in[4];
    const float* fc_w = (const float*)d_in[5];
    const float* fc_b = (const float*)d_in[6];
    float* out = (float*)d_out;

    dim3 grid(1024);   // 4096 rows / 4 per block
    dim3 block(128);   // 2 waves: unit-split, 2048 waves = 2/SIMD
    gru_2w<<<grid, block, 0, stream>>>(x, w_ih, w_hh, b_ih, b_hh, fc_w, fc_b, out);
}